// Round 1
// baseline (3259.529 us; speedup 1.0000x reference)
//
#include <hip/hip_runtime.h>
#include <hip/hip_bf16.h>

typedef short bf16x8 __attribute__((ext_vector_type(8)));
typedef float f32x4  __attribute__((ext_vector_type(4)));

#define BB 64
#define SS 512
#define EE 300
#define EP 320          // E padded to multiple of 32
#define HH 512

// workspace layout (bytes)
#define XBF_OFF    ((size_t)0)
#define XBF_BYTES  ((size_t)BB*SS*EP*2)          // 20,971,520
#define HBUF_OFF   (XBF_OFF + XBF_BYTES)
#define HBUF_BYTES ((size_t)2*BB*HH*2)           // 131,072
#define HT_OFF     (HBUF_OFF + HBUF_BYTES)
#define HT_BYTES   ((size_t)BB*HH*4)             // 131,072
#define FLAGS_OFF  (HT_OFF + HT_BYTES)
#define FLAGS_BYTES ((size_t)64*32*4)            // 8,192 (one flag per wg, 128B apart)

__device__ __forceinline__ unsigned short f2bf(float x) {
  union { float f; unsigned u; } v; v.f = x;
  unsigned r = v.u + 0x7fffu + ((v.u >> 16) & 1u);   // RNE
  return (unsigned short)(r >> 16);
}

// ---- phase 0: embedding gather + cast to bf16, pad E->EP with zeros ----
__global__ void gather_cast_kernel(const int* __restrict__ idx,
                                   const float* __restrict__ emb,
                                   unsigned short* __restrict__ xbf) {
  int row = blockIdx.x;                    // b*SS + t
  int v = idx[row];
  const float* src = emb + (size_t)v * EE;
  unsigned short* dst = xbf + (size_t)row * EP;
  for (int e = threadIdx.x; e < EP; e += 64)
    dst[e] = (e < EE) ? f2bf(src[e]) : (unsigned short)0;
}

// ---- phase 1: persistent recurrence. wg p owns hidden units [8p, 8p+8). ----
// 8 waves = 4 m-tiles (16 samples each) x 2 k-halves. W fragments live in VGPRs.
__launch_bounds__(512, 2)
__global__ void lstm_kernel(const unsigned short* __restrict__ xbf,
                            unsigned short* __restrict__ hbuf,   // [2][BB][HH] bf16
                            float* __restrict__ hT,              // [BB][HH] fp32
                            int* __restrict__ flags,             // [64][32]
                            const float* __restrict__ Wih,
                            const float* __restrict__ Whh,
                            const float* __restrict__ bih,
                            const float* __restrict__ bhh) {
  __shared__ float gates_lds[2][64][33];   // [kh][sample][gatecol], +1 pad
  __shared__ float bias_lds[32];

  const int p    = blockIdx.x;             // 0..63
  const int tid  = threadIdx.x;            // 0..511
  const int lane = tid & 63;
  const int w    = tid >> 6;
  const int mt   = w & 3;                  // m-tile (samples 16mt..16mt+15)
  const int kh   = w >> 2;                 // k-half (0/1)
  const int col  = lane & 15;
  const int kg   = lane >> 4;              // 0..3

  // ---- preload W fragments into registers (constant for all 512 steps) ----
  // B[k][n] = W[G(n)][k]; lane: n = 16*nt+col, k = k0 + 8*kg + j
  bf16x8 Bx[2][5];                         // x-part: K=320 -> 2 halves of 160 (5 ksteps)
  bf16x8 Bh[2][8];                         // h-part: K=512 -> 2 halves of 256 (8 ksteps)
  #pragma unroll
  for (int nt = 0; nt < 2; ++nt) {
    int n = nt * 16 + col;                                  // slice col 0..31
    int Grow = ((n >> 3) << 9) + (p << 3) + (n & 7);        // global gate row
    const float* wih_row = Wih + (size_t)Grow * EE;
    const float* whh_row = Whh + (size_t)Grow * HH;
    #pragma unroll
    for (int ks = 0; ks < 5; ++ks) {
      int k0 = 160 * kh + 32 * ks + 8 * kg;
      bf16x8 vb;
      #pragma unroll
      for (int j = 0; j < 8; ++j) {
        int k = k0 + j;
        float f = (k < EE) ? wih_row[k] : 0.f;
        vb[j] = (short)f2bf(f);
      }
      Bx[nt][ks] = vb;
    }
    #pragma unroll
    for (int ks = 0; ks < 8; ++ks) {
      int k0 = 256 * kh + 32 * ks + 8 * kg;
      bf16x8 vb;
      #pragma unroll
      for (int j = 0; j < 8; ++j) vb[j] = (short)f2bf(whh_row[k0 + j]);
      Bh[nt][ks] = vb;
    }
  }
  if (tid < 32) {
    int Grow = ((tid >> 3) << 9) + (p << 3) + (tid & 7);
    bias_lds[tid] = bih[Grow] + bhh[Grow];
  }

  // update-phase mapping: thread -> (sample, unit)
  const int us = tid >> 3;
  const int uu = tid & 7;
  float c_reg = 0.f;                       // cell state, fp32, thread-private

  // A-load bases (per lane): A row = sample s0, k = k-base + 32*ks
  const int s0 = 16 * mt + col;
  const unsigned short* xa = xbf + (size_t)s0 * SS * EP + 160 * kh + 8 * kg;
  const int arow = s0 * HH + 256 * kh + 8 * kg;

  int* myflag = flags + (p << 5);

  for (int it = 0; it < 512; ++it) {
    f32x4 acc0 = {0.f, 0.f, 0.f, 0.f};
    f32x4 acc1 = {0.f, 0.f, 0.f, 0.f};

    // --- x part (no cross-wg dependency; overlaps peers' publishing) ---
    const unsigned short* xp = xa + (size_t)it * EP;
    #pragma unroll
    for (int ks = 0; ks < 5; ++ks) {
      bf16x8 a = *(const bf16x8*)(xp + 32 * ks);
      acc0 = __builtin_amdgcn_mfma_f32_16x16x32_bf16(a, Bx[0][ks], acc0, 0, 0, 0);
      acc1 = __builtin_amdgcn_mfma_f32_16x16x32_bf16(a, Bx[1][ks], acc1, 0, 0, 0);
    }

    // --- wait until every wg has published h(it) ---
    if (it > 0) {
      if (tid < 64) {
        const int* f = flags + (tid << 5);
        while (__hip_atomic_load(f, __ATOMIC_RELAXED, __HIP_MEMORY_SCOPE_AGENT) < it)
          __builtin_amdgcn_s_sleep(1);
      }
      if (tid == 0) __builtin_amdgcn_fence(__ATOMIC_ACQUIRE, "agent");
      __syncthreads();
    }

    // --- h part ---
    const unsigned short* hp = hbuf + (size_t)(it & 1) * (BB * HH) + arow;
    #pragma unroll
    for (int ks = 0; ks < 8; ++ks) {
      bf16x8 a = *(const bf16x8*)(hp + 32 * ks);
      acc0 = __builtin_amdgcn_mfma_f32_16x16x32_bf16(a, Bh[0][ks], acc0, 0, 0, 0);
      acc1 = __builtin_amdgcn_mfma_f32_16x16x32_bf16(a, Bh[1][ks], acc1, 0, 0, 0);
    }

    // --- epilogue: D row=(kg*4+r)+16mt (sample), col=lane&15 (gate col) ---
    #pragma unroll
    for (int r = 0; r < 4; ++r) {
      gates_lds[kh][16 * mt + 4 * kg + r][col]      = acc0[r];
      gates_lds[kh][16 * mt + 4 * kg + r][16 + col] = acc1[r];
    }
    __syncthreads();

    // --- gate math (fp32), h/c update ---
    {
      float gi = gates_lds[0][us][uu]      + gates_lds[1][us][uu]      + bias_lds[uu];
      float gf = gates_lds[0][us][uu + 8]  + gates_lds[1][us][uu + 8]  + bias_lds[uu + 8];
      float gg = gates_lds[0][us][uu + 16] + gates_lds[1][us][uu + 16] + bias_lds[uu + 16];
      float go = gates_lds[0][us][uu + 24] + gates_lds[1][us][uu + 24] + bias_lds[uu + 24];
      float ig = 1.f / (1.f + __expf(-gi));
      float fg = 1.f / (1.f + __expf(-gf));
      float og = 1.f / (1.f + __expf(-go));
      float gt = tanhf(gg);
      c_reg = fg * c_reg + ig * gt;
      float h = og * tanhf(c_reg);
      hbuf[(size_t)((it + 1) & 1) * (BB * HH) + us * HH + (p << 3) + uu] = f2bf(h);
      if (it == 511) hT[us * HH + (p << 3) + uu] = h;
    }
    __syncthreads();   // drains stores (vmcnt 0 before barrier) + gates_lds WAR

    if (tid == 0) {
      __builtin_amdgcn_fence(__ATOMIC_RELEASE, "agent");
      __hip_atomic_store(myflag, it + 1, __ATOMIC_RELAXED, __HIP_MEMORY_SCOPE_AGENT);
    }
  }
}

// ---- phase 2: y[b] = hT[b,:] . Wout + bout ----
__global__ void outproj_kernel(const float* __restrict__ hT,
                               const float* __restrict__ Wout,
                               const float* __restrict__ bout,
                               float* __restrict__ y) {
  int b = blockIdx.x;
  int t = threadIdx.x;   // 64
  float s = 0.f;
  for (int j = t; j < HH; j += 64) s += hT[b * HH + j] * Wout[j];
  #pragma unroll
  for (int off = 32; off > 0; off >>= 1) s += __shfl_down(s, off, 64);
  if (t == 0) y[b] = s + bout[0];
}

extern "C" void kernel_launch(void* const* d_in, const int* in_sizes, int n_in,
                              void* d_out, int out_size, void* d_ws, size_t ws_size,
                              hipStream_t stream) {
  const int*   idx  = (const int*)d_in[0];
  const float* emb  = (const float*)d_in[1];
  const float* Wih  = (const float*)d_in[2];
  const float* Whh  = (const float*)d_in[3];
  const float* bih  = (const float*)d_in[4];
  const float* bhh  = (const float*)d_in[5];
  const float* Wout = (const float*)d_in[6];
  const float* bout = (const float*)d_in[7];
  float* y = (float*)d_out;

  char* ws = (char*)d_ws;
  unsigned short* xbf  = (unsigned short*)(ws + XBF_OFF);
  unsigned short* hbuf = (unsigned short*)(ws + HBUF_OFF);
  float* hT            = (float*)(ws + HT_OFF);
  int* flags           = (int*)(ws + FLAGS_OFF);

  // deterministic per-call init: h(0)=0 and flags=0
  hipMemsetAsync(ws + HBUF_OFF, 0, (size_t)BB * HH * 2, stream);
  hipMemsetAsync(ws + FLAGS_OFF, 0, FLAGS_BYTES, stream);

  gather_cast_kernel<<<BB * SS, 64, 0, stream>>>(idx, emb, xbf);
  lstm_kernel<<<64, 512, 0, stream>>>(xbf, hbuf, hT, flags, Wih, Whh, bih, bhh);
  outproj_kernel<<<BB, 64, 0, stream>>>(hT, Wout, bout, y);
}